// Round 6
// baseline (231.819 us; speedup 1.0000x reference)
//
#include <hip/hip_runtime.h>
#include <hip/hip_cooperative_groups.h>
#include <hip/hip_bf16.h>

namespace cg = cooperative_groups;

#define ALPHA_C 0.3f
#define BETHE_C 1.2f
#define CH 4   // j-panels (64 rows each) per chunk

typedef __attribute__((ext_vector_type(8))) short  frag_ab;   // 8 bf16 = 4 VGPR
typedef __attribute__((ext_vector_type(4))) float  frag_cd;   // 4 fp32 acc

// fp32 -> bf16 round-to-nearest-even
static __device__ __forceinline__ unsigned short f2bf(float f) {
    union { float f; unsigned int u; } cv;
    cv.f = f;
    unsigned int x = cv.u;
    unsigned int r = (x + 0x7fffu + ((x >> 16) & 1u)) >> 16;
    return (unsigned short)r;
}

__global__ void zero_kernel(float* out) { out[0] = 0.0f; }

// ================= single-dispatch cooperative kernel =================
// Phase 0: X fp32 [N][128] -> Xb bf16 FRAGMENT-LINEAR (tile T = R*4+ks is
//          1 KB contiguous; lane l's 16 B at T*1024 + l*16).
// Phase 1: wave w owns row-panel i = w & (NP-1); chunks c = w>>7 and
//          NC-1-(w>>7) (anti-paired for balance). A panel register-resident.
// Phase 2: block 0 reduces per-wave partials deterministically.
__global__ __launch_bounds__(256, 2) void margin_fused(
    const float* __restrict__ X, const int* __restrict__ labels,
    unsigned short* __restrict__ Xb, float* __restrict__ partials,
    float* __restrict__ out, int N, float inv_n)
{
    __shared__ float wsum[4];
    const int t    = threadIdx.x;
    const int lane = t & 63;
    const int wblk = t >> 6;
    const int NP   = N >> 6;                  // 64-row panels (128)
    const int GW   = gridDim.x << 2;          // total waves (2048)

    // ---------- phase 0: convert ----------
    for (int tau = blockIdx.x * 256 + t; tau < N * 16; tau += gridDim.x * 256) {
        const int T = tau >> 6;
        const int l = tau & 63;
        const int R  = T >> 2;
        const int ks = T & 3;
        const int row = R * 16 + (l & 15);
        const int k   = ks * 32 + (l >> 4) * 8;
        const float* src = X + (size_t)row * 128 + k;
        float4 a0 = *(const float4*)(src);
        float4 a1 = *(const float4*)(src + 4);
        frag_ab p;
        p[0] = (short)f2bf(a0.x); p[1] = (short)f2bf(a0.y);
        p[2] = (short)f2bf(a0.z); p[3] = (short)f2bf(a0.w);
        p[4] = (short)f2bf(a1.x); p[5] = (short)f2bf(a1.y);
        p[6] = (short)f2bf(a1.z); p[7] = (short)f2bf(a1.w);
        *(frag_ab*)((char*)Xb + (size_t)T * 1024 + l * 16) = p;
    }

    __threadfence();
    cg::this_grid().sync();

    // ---------- phase 1: Gram + hinge ----------
    const int gwave = blockIdx.x * 4 + wblk;       // 0..GW-1
    const int i     = gwave & (NP - 1);            // row panel
    const int cbase = gwave / NP;                  // 0..GW/NP-1
    const int NC    = (NP + CH - 1) / CH;          // chunk count (32)
    const int l     = lane;

    // A fragments (row-tiles i*4+m, 4 k-steps) -> 64 VGPRs; per-lane A labels
    frag_ab avv[4][4];   // [ks][m]
    #pragma unroll
    for (int m = 0; m < 4; ++m)
        #pragma unroll
        for (int ks = 0; ks < 4; ++ks)
            avv[ks][m] = *(const frag_ab*)(Xb +
                (size_t)((i * 4 + m) * 4 + ks) * 512 + l * 8);

    int labi[4][4];
    #pragma unroll
    for (int m = 0; m < 4; ++m)
        #pragma unroll
        for (int r4 = 0; r4 < 4; ++r4)
            labi[m][r4] = labels[i * 64 + m * 16 + ((l >> 4) << 2) + r4];

    float lsum = 0.f;

    #pragma unroll
    for (int s = 0; s < 2; ++s) {
        const int c  = (s == 0) ? cbase : (NC - 1 - cbase);
        const int j0 = i + c * CH;
        if (j0 < NP) {
            const int nj = min(CH, NP - j0);
            for (int jj = 0; jj < nj; ++jj) {
                const int j = j0 + jj;

                frag_cd acc[4][4];
                #pragma unroll
                for (int m = 0; m < 4; ++m)
                    #pragma unroll
                    for (int n = 0; n < 4; ++n)
                        acc[m][n] = (frag_cd){0.f, 0.f, 0.f, 0.f};

                #pragma unroll
                for (int ks = 0; ks < 4; ++ks) {
                    frag_ab bv[4];
                    #pragma unroll
                    for (int n = 0; n < 4; ++n)
                        bv[n] = *(const frag_ab*)(Xb +
                            (size_t)((j * 4 + n) * 4 + ks) * 512 + l * 8);
                    #pragma unroll
                    for (int m = 0; m < 4; ++m)
                        #pragma unroll
                        for (int n = 0; n < 4; ++n)
                            acc[m][n] = __builtin_amdgcn_mfma_f32_16x16x32_bf16(
                                avv[ks][m], bv[n], acc[m][n], 0, 0, 0);
                }

                int labj[4];
                #pragma unroll
                for (int n = 0; n < 4; ++n)
                    labj[n] = labels[j * 64 + n * 16 + (l & 15)];

                float ts = 0.f;
                #pragma unroll
                for (int m = 0; m < 4; ++m) {
                    #pragma unroll
                    for (int r4 = 0; r4 < 4; ++r4) {
                        const int li = labi[m][r4];
                        #pragma unroll
                        for (int n = 0; n < 4; ++n) {
                            const float d = acc[m][n][r4];
                            const float v = (li == labj[n])
                                ? (d + (ALPHA_C - BETHE_C))
                                : ((ALPHA_C + BETHE_C) - d);
                            ts += fmaxf(v, 0.f);
                        }
                    }
                }
                lsum += (j == i) ? ts : 2.f * ts;
            }
        }
    }

    #pragma unroll
    for (int off = 32; off > 0; off >>= 1)
        lsum += __shfl_down(lsum, off, 64);
    if (lane == 0) partials[gwave] = lsum;

    __threadfence();
    cg::this_grid().sync();

    // ---------- phase 2: deterministic final reduce ----------
    if (blockIdx.x == 0) {
        float s = 0.f;
        for (int idx = t; idx < GW; idx += 256) s += partials[idx];
        #pragma unroll
        for (int off = 32; off > 0; off >>= 1)
            s += __shfl_down(s, off, 64);
        if (lane == 0) wsum[wblk] = s;
        __syncthreads();
        if (t == 0) out[0] = (wsum[0] + wsum[1] + wsum[2] + wsum[3]) * inv_n;
    }
}

// ================= fallback path (round-5, 3 dispatches) =================
__global__ __launch_bounds__(256) void convert_kernel(
    const float* __restrict__ X, unsigned short* __restrict__ Xb, int nrows)
{
    const int tau = blockIdx.x * 256 + threadIdx.x;
    const int total = nrows * 16;
    if (tau >= total) return;
    const int T = tau >> 6;
    const int l = tau & 63;
    const int R  = T >> 2;
    const int ks = T & 3;
    const int row = R * 16 + (l & 15);
    const int k   = ks * 32 + (l >> 4) * 8;
    const float* src = X + (size_t)row * 128 + k;
    float4 a0 = *(const float4*)(src);
    float4 a1 = *(const float4*)(src + 4);
    frag_ab p;
    p[0] = (short)f2bf(a0.x); p[1] = (short)f2bf(a0.y);
    p[2] = (short)f2bf(a0.z); p[3] = (short)f2bf(a0.w);
    p[4] = (short)f2bf(a1.x); p[5] = (short)f2bf(a1.y);
    p[6] = (short)f2bf(a1.z); p[7] = (short)f2bf(a1.w);
    *(frag_ab*)((char*)Xb + (size_t)T * 1024 + l * 16) = p;
}

__global__ __launch_bounds__(64, 2) void margin_reg(
    const unsigned short* __restrict__ Xb, const int* __restrict__ labels,
    float* __restrict__ partials, int NP)
{
    const int i   = blockIdx.x;
    const int bid = blockIdx.y * gridDim.x + blockIdx.x;
    const int j0  = i + blockIdx.y * CH;
    const int l   = threadIdx.x;

    if (j0 >= NP) { if (l == 0) partials[bid] = 0.f; return; }
    const int nj = min(CH, NP - j0);

    frag_ab avv[4][4];
    #pragma unroll
    for (int m = 0; m < 4; ++m)
        #pragma unroll
        for (int ks = 0; ks < 4; ++ks)
            avv[ks][m] = *(const frag_ab*)(Xb +
                (size_t)((i * 4 + m) * 4 + ks) * 512 + l * 8);

    int labi[4][4];
    #pragma unroll
    for (int m = 0; m < 4; ++m)
        #pragma unroll
        for (int r4 = 0; r4 < 4; ++r4)
            labi[m][r4] = labels[i * 64 + m * 16 + ((l >> 4) << 2) + r4];

    float lsum = 0.f;
    for (int jj = 0; jj < nj; ++jj) {
        const int j = j0 + jj;
        frag_cd acc[4][4];
        #pragma unroll
        for (int m = 0; m < 4; ++m)
            #pragma unroll
            for (int n = 0; n < 4; ++n)
                acc[m][n] = (frag_cd){0.f, 0.f, 0.f, 0.f};
        #pragma unroll
        for (int ks = 0; ks < 4; ++ks) {
            frag_ab bv[4];
            #pragma unroll
            for (int n = 0; n < 4; ++n)
                bv[n] = *(const frag_ab*)(Xb +
                    (size_t)((j * 4 + n) * 4 + ks) * 512 + l * 8);
            #pragma unroll
            for (int m = 0; m < 4; ++m)
                #pragma unroll
                for (int n = 0; n < 4; ++n)
                    acc[m][n] = __builtin_amdgcn_mfma_f32_16x16x32_bf16(
                        avv[ks][m], bv[n], acc[m][n], 0, 0, 0);
        }
        int labj[4];
        #pragma unroll
        for (int n = 0; n < 4; ++n)
            labj[n] = labels[j * 64 + n * 16 + (l & 15)];
        float ts = 0.f;
        #pragma unroll
        for (int m = 0; m < 4; ++m)
            #pragma unroll
            for (int r4 = 0; r4 < 4; ++r4) {
                const int li = labi[m][r4];
                #pragma unroll
                for (int n = 0; n < 4; ++n) {
                    const float d = acc[m][n][r4];
                    const float v = (li == labj[n])
                        ? (d + (ALPHA_C - BETHE_C))
                        : ((ALPHA_C + BETHE_C) - d);
                    ts += fmaxf(v, 0.f);
                }
            }
        lsum += (j == i) ? ts : 2.f * ts;
    }

    #pragma unroll
    for (int off = 32; off > 0; off >>= 1)
        lsum += __shfl_down(lsum, off, 64);
    if (l == 0) partials[bid] = lsum;
}

__global__ __launch_bounds__(256) void reduce_kernel(
    const float* __restrict__ partials, float* __restrict__ out,
    int n, float inv_n)
{
    __shared__ float wsum[4];
    const int t    = threadIdx.x;
    const int lane = t & 63;
    const int wid  = t >> 6;
    float s = 0.f;
    for (int idx = t; idx < n; idx += 256) s += partials[idx];
    #pragma unroll
    for (int off = 32; off > 0; off >>= 1)
        s += __shfl_down(s, off, 64);
    if (lane == 0) wsum[wid] = s;
    __syncthreads();
    if (t == 0) out[0] = (wsum[0] + wsum[1] + wsum[2] + wsum[3]) * inv_n;
}

// ---------------- last-resort fallback (tiny ws): round-1 fused kernel ----------------
__global__ __launch_bounds__(256) void margin_tile_kernel(
    const float* __restrict__ X, const int* __restrict__ labels,
    float* __restrict__ out, int NT, float inv_n)
{
    __shared__ unsigned short ldsA[128 * 64];
    __shared__ unsigned short ldsB[128 * 64];
    __shared__ int labA[128];
    __shared__ int labB[128];
    __shared__ float wsum[4];

    int b = blockIdx.x;
    int ti = 0;
    while (b >= NT - ti) { b -= NT - ti; ++ti; }
    const int tj = ti + b;

    const int t    = threadIdx.x;
    const int lane = t & 63;
    const int wid  = t >> 6;
    const int wr   = wid >> 1;
    const int wc   = wid & 1;

    const int rowA = ti * 128;
    const int rowB = tj * 128;

    if (t < 128) labA[t] = labels[rowA + t];
    else         labB[t - 128] = labels[rowB + (t - 128)];

    frag_cd acc[4][4];
    #pragma unroll
    for (int m = 0; m < 4; ++m)
        #pragma unroll
        for (int n = 0; n < 4; ++n)
            acc[m][n] = (frag_cd){0.f, 0.f, 0.f, 0.f};

    const int g  = lane >> 4;
    const int rl = lane & 15;

    for (int kh = 0; kh < 2; ++kh) {
        __syncthreads();
        #pragma unroll
        for (int it = 0; it < 4; ++it) {
            const int c  = it * 256 + t;
            const int r  = c >> 3;
            const int c8 = c & 7;
            const float* srcA = X + (size_t)(rowA + r) * 128 + kh * 64 + c8 * 8;
            const float* srcB = X + (size_t)(rowB + r) * 128 + kh * 64 + c8 * 8;
            float4 a0 = *(const float4*)(srcA);
            float4 a1 = *(const float4*)(srcA + 4);
            float4 b0 = *(const float4*)(srcB);
            float4 b1 = *(const float4*)(srcB + 4);
            const int byte = r * 128 + (((c8 << 4)) ^ ((r & 7) << 4));
            frag_ab pa, pb;
            pa[0] = (short)f2bf(a0.x); pa[1] = (short)f2bf(a0.y);
            pa[2] = (short)f2bf(a0.z); pa[3] = (short)f2bf(a0.w);
            pa[4] = (short)f2bf(a1.x); pa[5] = (short)f2bf(a1.y);
            pa[6] = (short)f2bf(a1.z); pa[7] = (short)f2bf(a1.w);
            pb[0] = (short)f2bf(b0.x); pb[1] = (short)f2bf(b0.y);
            pb[2] = (short)f2bf(b0.z); pb[3] = (short)f2bf(b0.w);
            pb[4] = (short)f2bf(b1.x); pb[5] = (short)f2bf(b1.y);
            pb[6] = (short)f2bf(b1.z); pb[7] = (short)f2bf(b1.w);
            *(frag_ab*)((char*)ldsA + byte) = pa;
            *(frag_ab*)((char*)ldsB + byte) = pb;
        }
        __syncthreads();
        #pragma unroll
        for (int ks = 0; ks < 2; ++ks) {
            const int kbyte = ks * 64 + g * 16;
            frag_ab av[4], bv[4];
            #pragma unroll
            for (int m = 0; m < 4; ++m) {
                const int row = wr * 64 + m * 16 + rl;
                av[m] = *(const frag_ab*)((const char*)ldsA +
                            row * 128 + (kbyte ^ ((row & 7) << 4)));
            }
            #pragma unroll
            for (int n = 0; n < 4; ++n) {
                const int row = wc * 64 + n * 16 + rl;
                bv[n] = *(const frag_ab*)((const char*)ldsB +
                            row * 128 + (kbyte ^ ((row & 7) << 4)));
            }
            #pragma unroll
            for (int m = 0; m < 4; ++m)
                #pragma unroll
                for (int n = 0; n < 4; ++n)
                    acc[m][n] = __builtin_amdgcn_mfma_f32_16x16x32_bf16(
                        av[m], bv[n], acc[m][n], 0, 0, 0);
        }
    }

    float lsum = 0.f;
    const int oc  = lane & 15;
    const int orr = (lane >> 4) * 4;

    int lj[4];
    #pragma unroll
    for (int n = 0; n < 4; ++n) lj[n] = labB[wc * 64 + n * 16 + oc];

    #pragma unroll
    for (int m = 0; m < 4; ++m) {
        #pragma unroll
        for (int j = 0; j < 4; ++j) {
            const int li = labA[wr * 64 + m * 16 + orr + j];
            #pragma unroll
            for (int n = 0; n < 4; ++n) {
                const float d = acc[m][n][j];
                const float s = (li == lj[n]) ? 1.f : -1.f;
                lsum += fmaxf(fmaf(s, d - BETHE_C, ALPHA_C), 0.f);
            }
        }
    }

    const float w = (ti == tj) ? 1.f : 2.f;
    lsum *= w * inv_n;

    #pragma unroll
    for (int off = 32; off > 0; off >>= 1)
        lsum += __shfl_down(lsum, off, 64);

    if (lane == 0) wsum[wid] = lsum;
    __syncthreads();
    if (t == 0) atomicAdd(out, wsum[0] + wsum[1] + wsum[2] + wsum[3]);
}

extern "C" void kernel_launch(void* const* d_in, const int* in_sizes, int n_in,
                              void* d_out, int out_size, void* d_ws, size_t ws_size,
                              hipStream_t stream) {
    const float* X      = (const float*)d_in[0];
    const int*   labels = (const int*)d_in[1];
    float*       out    = (float*)d_out;

    const int N = in_sizes[1];               // 8192

    const size_t xb_bytes = (size_t)N * 128 * sizeof(unsigned short);  // 2 MB
    const int GRID  = 512;                   // co-resident: 2 waves/SIMD guaranteed
    const int GW    = GRID * 4;              // 2048 waves
    const size_t need_coop = xb_bytes + (size_t)GW * sizeof(float);

    bool done = false;
    if (N == 8192 && ws_size >= need_coop) {
        unsigned short* Xb       = (unsigned short*)d_ws;
        float*          partials = (float*)((char*)d_ws + xb_bytes);
        int   Nv    = N;
        float inv_n = 1.0f / (float)N;
        void* args[] = { (void*)&X, (void*)&labels, (void*)&Xb,
                         (void*)&partials, (void*)&out, (void*)&Nv, (void*)&inv_n };
        hipError_t err = hipLaunchCooperativeKernel(
            (void*)margin_fused, dim3(GRID), dim3(256), args, 0, stream);
        done = (err == hipSuccess);
    }

    if (!done) {
        const int NP    = N / 64;
        const int NCHY  = (NP + CH - 1) / CH;
        const int npart = NP * NCHY;
        const size_t need = xb_bytes + (size_t)npart * sizeof(float);
        if ((N % 64) == 0 && ws_size >= need) {
            unsigned short* Xb       = (unsigned short*)d_ws;
            float*          partials = (float*)((char*)d_ws + xb_bytes);
            const int cblocks = (N * 16 + 255) / 256;
            convert_kernel<<<cblocks, 256, 0, stream>>>(X, Xb, N);
            margin_reg<<<dim3(NP, NCHY), 64, 0, stream>>>(Xb, labels, partials, NP);
            reduce_kernel<<<1, 256, 0, stream>>>(partials, out, npart, 1.0f / (float)N);
        } else {
            const int NT = N / 128;
            const int nblocks = NT * (NT + 1) / 2;
            zero_kernel<<<1, 1, 0, stream>>>(out);
            margin_tile_kernel<<<nblocks, 256, 0, stream>>>(X, labels, out, NT, 1.0f / (float)N);
        }
    }
}

// Round 7
// 107.810 us; speedup vs baseline: 2.1503x; 2.1503x over previous
//
#include <hip/hip_runtime.h>
#include <hip/hip_bf16.h>

#define ALPHA_C 0.3f
#define BETHE_C 1.2f
#define CH 4    // j-panels (64 rows each) per block
#define REP 8   // compute-replication probe (numerically inert, kept via asm)

typedef __attribute__((ext_vector_type(8))) short  frag_ab;   // 8 bf16 = 4 VGPR
typedef __attribute__((ext_vector_type(4))) float  frag_cd;   // 4 fp32 acc

// fp32 -> bf16 round-to-nearest-even
static __device__ __forceinline__ unsigned short f2bf(float f) {
    union { float f; unsigned int u; } cv;
    cv.f = f;
    unsigned int x = cv.u;
    unsigned int r = (x + 0x7fffu + ((x >> 16) & 1u)) >> 16;
    return (unsigned short)r;
}

__global__ void zero_kernel(float* out) { out[0] = 0.0f; }

// Pre-pass: X fp32 [N][128] -> Xb bf16 in FRAGMENT-LINEAR layout.
// Tile T = R*4 + ks; lane l's 16 B at byte T*1024 + l*16.
__global__ __launch_bounds__(256) void convert_kernel(
    const float* __restrict__ X, unsigned short* __restrict__ Xb, int nrows)
{
    const int tau = blockIdx.x * 256 + threadIdx.x;
    const int total = nrows * 16;
    if (tau >= total) return;
    const int T = tau >> 6;
    const int l = tau & 63;
    const int R  = T >> 2;
    const int ks = T & 3;
    const int row = R * 16 + (l & 15);
    const int k   = ks * 32 + (l >> 4) * 8;
    const float* src = X + (size_t)row * 128 + k;
    float4 a0 = *(const float4*)(src);
    float4 a1 = *(const float4*)(src + 4);
    frag_ab p;
    p[0] = (short)f2bf(a0.x); p[1] = (short)f2bf(a0.y);
    p[2] = (short)f2bf(a0.z); p[3] = (short)f2bf(a0.w);
    p[4] = (short)f2bf(a1.x); p[5] = (short)f2bf(a1.y);
    p[6] = (short)f2bf(a1.z); p[7] = (short)f2bf(a1.w);
    *(frag_ab*)((char*)Xb + (size_t)T * 1024 + l * 16) = p;
}

// Main (r5 structure + REP-replication probe): 1 wave per block, no LDS,
// no barriers. Block (i, c) computes 64x64 tiles (i, j), j = i+c*CH .. +CH.
__global__ __launch_bounds__(64, 2) void margin_reg(
    const unsigned short* __restrict__ Xb, const int* __restrict__ labels,
    float* __restrict__ partials, int NP)
{
    const int i   = blockIdx.x;
    const int bid = blockIdx.y * gridDim.x + blockIdx.x;
    const int j0  = i + blockIdx.y * CH;
    const int l   = threadIdx.x;

    if (j0 >= NP) { if (l == 0) partials[bid] = 0.f; return; }
    const int nj = min(CH, NP - j0);

    // A fragments register-resident
    frag_ab avv[4][4];   // [ks][m]
    #pragma unroll
    for (int m = 0; m < 4; ++m)
        #pragma unroll
        for (int ks = 0; ks < 4; ++ks)
            avv[ks][m] = *(const frag_ab*)(Xb +
                (size_t)((i * 4 + m) * 4 + ks) * 512 + l * 8);

    int labi[4][4];
    #pragma unroll
    for (int m = 0; m < 4; ++m)
        #pragma unroll
        for (int r4 = 0; r4 < 4; ++r4)
            labi[m][r4] = labels[i * 64 + m * 16 + ((l >> 4) << 2) + r4];

    float lsum = 0.f;

    for (int jj = 0; jj < nj; ++jj) {
        const int j = j0 + jj;

        int labj[4];
        #pragma unroll
        for (int n = 0; n < 4; ++n)
            labj[n] = labels[j * 64 + n * 16 + (l & 15)];

        float ts = 0.f;

        // ---- replication probe: identical compute REP times; every rep's
        // result is kept live by an empty asm (no DCE, rule #17); the value
        // of ts after the loop equals the single-pass value exactly. ----
        #pragma unroll 1
        for (int rep = 0; rep < REP; ++rep) {
            frag_cd acc[4][4];
            #pragma unroll
            for (int m = 0; m < 4; ++m)
                #pragma unroll
                for (int n = 0; n < 4; ++n)
                    acc[m][n] = (frag_cd){0.f, 0.f, 0.f, 0.f};

            #pragma unroll
            for (int ks = 0; ks < 4; ++ks) {
                frag_ab bv[4];
                #pragma unroll
                for (int n = 0; n < 4; ++n)
                    bv[n] = *(const frag_ab*)(Xb +
                        (size_t)((j * 4 + n) * 4 + ks) * 512 + l * 8);
                #pragma unroll
                for (int m = 0; m < 4; ++m)
                    #pragma unroll
                    for (int n = 0; n < 4; ++n)
                        acc[m][n] = __builtin_amdgcn_mfma_f32_16x16x32_bf16(
                            avv[ks][m], bv[n], acc[m][n], 0, 0, 0);
            }

            float tr = 0.f;
            #pragma unroll
            for (int m = 0; m < 4; ++m) {
                #pragma unroll
                for (int r4 = 0; r4 < 4; ++r4) {
                    const int li = labi[m][r4];
                    #pragma unroll
                    for (int n = 0; n < 4; ++n) {
                        const float d = acc[m][n][r4];
                        const float v = (li == labj[n])
                            ? (d + (ALPHA_C - BETHE_C))
                            : ((ALPHA_C + BETHE_C) - d);
                        tr += fmaxf(v, 0.f);
                    }
                }
            }
            asm volatile("" :: "v"(tr));   // keep this rep's chain alive
            ts = tr;                        // same value every rep
        }

        lsum += (j == i) ? ts : 2.f * ts;
    }

    #pragma unroll
    for (int off = 32; off > 0; off >>= 1)
        lsum += __shfl_down(lsum, off, 64);
    if (l == 0) partials[bid] = lsum;
}

// Final reduce: one block sums partials (fixed order -> deterministic).
__global__ __launch_bounds__(256) void reduce_kernel(
    const float* __restrict__ partials, float* __restrict__ out,
    int n, float inv_n)
{
    __shared__ float wsum[4];
    const int t    = threadIdx.x;
    const int lane = t & 63;
    const int wid  = t >> 6;
    float s = 0.f;
    for (int idx = t; idx < n; idx += 256) s += partials[idx];
    #pragma unroll
    for (int off = 32; off > 0; off >>= 1)
        s += __shfl_down(s, off, 64);
    if (lane == 0) wsum[wid] = s;
    __syncthreads();
    if (t == 0) out[0] = (wsum[0] + wsum[1] + wsum[2] + wsum[3]) * inv_n;
}

// ---------------- fallback (tiny ws / odd N): round-1 fused kernel ----------------
__global__ __launch_bounds__(256) void margin_tile_kernel(
    const float* __restrict__ X, const int* __restrict__ labels,
    float* __restrict__ out, int NT, float inv_n)
{
    __shared__ unsigned short ldsA[128 * 64];
    __shared__ unsigned short ldsB[128 * 64];
    __shared__ int labA[128];
    __shared__ int labB[128];
    __shared__ float wsum[4];

    int b = blockIdx.x;
    int ti = 0;
    while (b >= NT - ti) { b -= NT - ti; ++ti; }
    const int tj = ti + b;

    const int t    = threadIdx.x;
    const int lane = t & 63;
    const int wid  = t >> 6;
    const int wr   = wid >> 1;
    const int wc   = wid & 1;

    const int rowA = ti * 128;
    const int rowB = tj * 128;

    if (t < 128) labA[t] = labels[rowA + t];
    else         labB[t - 128] = labels[rowB + (t - 128)];

    frag_cd acc[4][4];
    #pragma unroll
    for (int m = 0; m < 4; ++m)
        #pragma unroll
        for (int n = 0; n < 4; ++n)
            acc[m][n] = (frag_cd){0.f, 0.f, 0.f, 0.f};

    const int g  = lane >> 4;
    const int rl = lane & 15;

    for (int kh = 0; kh < 2; ++kh) {
        __syncthreads();
        #pragma unroll
        for (int it = 0; it < 4; ++it) {
            const int c  = it * 256 + t;
            const int r  = c >> 3;
            const int c8 = c & 7;
            const float* srcA = X + (size_t)(rowA + r) * 128 + kh * 64 + c8 * 8;
            const float* srcB = X + (size_t)(rowB + r) * 128 + kh * 64 + c8 * 8;
            float4 a0 = *(const float4*)(srcA);
            float4 a1 = *(const float4*)(srcA + 4);
            float4 b0 = *(const float4*)(srcB);
            float4 b1 = *(const float4*)(srcB + 4);
            const int byte = r * 128 + (((c8 << 4)) ^ ((r & 7) << 4));
            frag_ab pa, pb;
            pa[0] = (short)f2bf(a0.x); pa[1] = (short)f2bf(a0.y);
            pa[2] = (short)f2bf(a0.z); pa[3] = (short)f2bf(a0.w);
            pa[4] = (short)f2bf(a1.x); pa[5] = (short)f2bf(a1.y);
            pa[6] = (short)f2bf(a1.z); pa[7] = (short)f2bf(a1.w);
            pb[0] = (short)f2bf(b0.x); pb[1] = (short)f2bf(b0.y);
            pb[2] = (short)f2bf(b0.z); pb[3] = (short)f2bf(b0.w);
            pb[4] = (short)f2bf(b1.x); pb[5] = (short)f2bf(b1.y);
            pb[6] = (short)f2bf(b1.z); pb[7] = (short)f2bf(b1.w);
            *(frag_ab*)((char*)ldsA + byte) = pa;
            *(frag_ab*)((char*)ldsB + byte) = pb;
        }
        __syncthreads();
        #pragma unroll
        for (int ks = 0; ks < 2; ++ks) {
            const int kbyte = ks * 64 + g * 16;
            frag_ab av[4], bv[4];
            #pragma unroll
            for (int m = 0; m < 4; ++m) {
                const int row = wr * 64 + m * 16 + rl;
                av[m] = *(const frag_ab*)((const char*)ldsA +
                            row * 128 + (kbyte ^ ((row & 7) << 4)));
            }
            #pragma unroll
            for (int n = 0; n < 4; ++n) {
                const int row = wc * 64 + n * 16 + rl;
                bv[n] = *(const frag_ab*)((const char*)ldsB +
                            row * 128 + (kbyte ^ ((row & 7) << 4)));
            }
            #pragma unroll
            for (int m = 0; m < 4; ++m)
                #pragma unroll
                for (int n = 0; n < 4; ++n)
                    acc[m][n] = __builtin_amdgcn_mfma_f32_16x16x32_bf16(
                        av[m], bv[n], acc[m][n], 0, 0, 0);
        }
    }

    float lsum = 0.f;
    const int oc  = lane & 15;
    const int orr = (lane >> 4) * 4;

    int lj[4];
    #pragma unroll
    for (int n = 0; n < 4; ++n) lj[n] = labB[wc * 64 + n * 16 + oc];

    #pragma unroll
    for (int m = 0; m < 4; ++m) {
        #pragma unroll
        for (int j = 0; j < 4; ++j) {
            const int li = labA[wr * 64 + m * 16 + orr + j];
            #pragma unroll
            for (int n = 0; n < 4; ++n) {
                const float d = acc[m][n][j];
                const float s = (li == lj[n]) ? 1.f : -1.f;
                lsum += fmaxf(fmaf(s, d - BETHE_C, ALPHA_C), 0.f);
            }
        }
    }

    const float w = (ti == tj) ? 1.f : 2.f;
    lsum *= w * inv_n;

    #pragma unroll
    for (int off = 32; off > 0; off >>= 1)
        lsum += __shfl_down(lsum, off, 64);

    if (lane == 0) wsum[wid] = lsum;
    __syncthreads();
    if (t == 0) atomicAdd(out, wsum[0] + wsum[1] + wsum[2] + wsum[3]);
}

extern "C" void kernel_launch(void* const* d_in, const int* in_sizes, int n_in,
                              void* d_out, int out_size, void* d_ws, size_t ws_size,
                              hipStream_t stream) {
    const float* X      = (const float*)d_in[0];
    const int*   labels = (const int*)d_in[1];
    float*       out    = (float*)d_out;

    const int N = in_sizes[1];               // 8192

    const size_t xb_bytes = (size_t)N * 128 * sizeof(unsigned short);  // 2 MB
    const int NP   = N / 64;                 // 128 panels
    const int NCHY = (NP + CH - 1) / CH;     // 32
    const int npart = NP * NCHY;             // 4096
    const size_t need = xb_bytes + (size_t)npart * sizeof(float);

    if ((N % 64) == 0 && ws_size >= need) {
        unsigned short* Xb       = (unsigned short*)d_ws;
        float*          partials = (float*)((char*)d_ws + xb_bytes);
        const int cblocks = (N * 16 + 255) / 256;
        convert_kernel<<<cblocks, 256, 0, stream>>>(X, Xb, N);
        margin_reg<<<dim3(NP, NCHY), 64, 0, stream>>>(Xb, labels, partials, NP);
        reduce_kernel<<<1, 256, 0, stream>>>(partials, out, npart, 1.0f / (float)N);
    } else {
        const int NT = N / 128;
        const int nblocks = NT * (NT + 1) / 2;
        zero_kernel<<<1, 1, 0, stream>>>(out);
        margin_tile_kernel<<<nblocks, 256, 0, stream>>>(X, labels, out, NT, 1.0f / (float)N);
    }
}

// Round 8
// 35.545 us; speedup vs baseline: 6.5218x; 3.0330x over previous
//
#include <hip/hip_runtime.h>
#include <hip/hip_bf16.h>

#define ALPHA_C 0.3f
#define BETHE_C 1.2f
#define CH 4    // j-panels (64 rows each) per block

typedef __attribute__((ext_vector_type(8))) short  frag_ab;   // 8 bf16 = 4 VGPR
typedef __attribute__((ext_vector_type(4))) float  frag_cd;   // 4 fp32 acc

// fp32 -> bf16 round-to-nearest-even
static __device__ __forceinline__ unsigned short f2bf(float f) {
    union { float f; unsigned int u; } cv;
    cv.f = f;
    unsigned int x = cv.u;
    unsigned int r = (x + 0x7fffu + ((x >> 16) & 1u)) >> 16;
    return (unsigned short)r;
}

__global__ void zero_kernel(float* out) { out[0] = 0.0f; }

// Pre-pass: X fp32 [N][128] -> Xb bf16 in FRAGMENT-LINEAR layout.
// Tile T = R*4 + ks; lane l's 16 B at byte T*1024 + l*16.
__global__ __launch_bounds__(256) void convert_kernel(
    const float* __restrict__ X, unsigned short* __restrict__ Xb, int nrows)
{
    const int tau = blockIdx.x * 256 + threadIdx.x;
    const int total = nrows * 16;
    if (tau >= total) return;
    const int T = tau >> 6;
    const int l = tau & 63;
    const int R  = T >> 2;
    const int ks = T & 3;
    const int row = R * 16 + (l & 15);
    const int k   = ks * 32 + (l >> 4) * 8;
    const float* src = X + (size_t)row * 128 + k;
    float4 a0 = *(const float4*)(src);
    float4 a1 = *(const float4*)(src + 4);
    frag_ab p;
    p[0] = (short)f2bf(a0.x); p[1] = (short)f2bf(a0.y);
    p[2] = (short)f2bf(a0.z); p[3] = (short)f2bf(a0.w);
    p[4] = (short)f2bf(a1.x); p[5] = (short)f2bf(a1.y);
    p[6] = (short)f2bf(a1.z); p[7] = (short)f2bf(a1.w);
    *(frag_ab*)((char*)Xb + (size_t)T * 1024 + l * 16) = p;
}

static __device__ __forceinline__ void load_bv(
    const unsigned short* __restrict__ Xb, int j, int ks, int l, frag_ab* bv)
{
    #pragma unroll
    for (int n = 0; n < 4; ++n)
        bv[n] = *(const frag_ab*)(Xb + (size_t)((j * 4 + n) * 4 + ks) * 512 + l * 8);
}

static __device__ __forceinline__ void mfma_step(
    const frag_ab* a /* avv[ks][.] */, const frag_ab* bv, frag_cd acc[4][4])
{
    #pragma unroll
    for (int m = 0; m < 4; ++m)
        #pragma unroll
        for (int n = 0; n < 4; ++n)
            acc[m][n] = __builtin_amdgcn_mfma_f32_16x16x32_bf16(
                a[m], bv[n], acc[m][n], 0, 0, 0);
}

// Main: 1 wave per block, no LDS, no barriers. Exact triangular grid:
// block b decodes (i, chunk) over counts ceil((NP-i)/CH); computes 64x64
// tiles (i, j), j = j0 .. j0+nj-1, with B-loads software-pipelined one
// k-step ahead (rotating bva/bvb register sets).
__global__ __launch_bounds__(64) void margin_reg(
    const unsigned short* __restrict__ Xb, const int* __restrict__ labels,
    float* __restrict__ partials, int NP)
{
    // triangular decode (<= NP scalar iterations)
    int b = blockIdx.x;
    int i = 0;
    while (true) {
        const int cnt = (NP - i + CH - 1) / CH;
        if (b < cnt) break;
        b -= cnt; ++i;
    }
    const int j0 = i + b * CH;
    const int nj = min(CH, NP - j0);
    const int l  = threadIdx.x;

    // A fragments register-resident: avv[ks][m]
    frag_ab avv[4][4];
    #pragma unroll
    for (int m = 0; m < 4; ++m)
        #pragma unroll
        for (int ks = 0; ks < 4; ++ks)
            avv[ks][m] = *(const frag_ab*)(Xb +
                (size_t)((i * 4 + m) * 4 + ks) * 512 + l * 8);

    int labi[4][4];
    #pragma unroll
    for (int m = 0; m < 4; ++m)
        #pragma unroll
        for (int r4 = 0; r4 < 4; ++r4)
            labi[m][r4] = labels[i * 64 + m * 16 + ((l >> 4) << 2) + r4];

    float lsum = 0.f;

    frag_ab bva[4], bvb[4];
    load_bv(Xb, j0, 0, l, bva);          // first tile ks=0 in flight early

    for (int jj = 0; jj < nj; ++jj) {
        const int j = j0 + jj;

        int labj[4];
        #pragma unroll
        for (int n = 0; n < 4; ++n)
            labj[n] = labels[j * 64 + n * 16 + (l & 15)];

        frag_cd acc[4][4];
        #pragma unroll
        for (int m = 0; m < 4; ++m)
            #pragma unroll
            for (int n = 0; n < 4; ++n)
                acc[m][n] = (frag_cd){0.f, 0.f, 0.f, 0.f};

        // pipelined K loop: issue loads one step ahead of the MFMAs
        load_bv(Xb, j, 1, l, bvb);
        mfma_step(avv[0], bva, acc);
        load_bv(Xb, j, 2, l, bva);
        mfma_step(avv[1], bvb, acc);
        load_bv(Xb, j, 3, l, bvb);
        mfma_step(avv[2], bva, acc);
        if (jj + 1 < nj) load_bv(Xb, j + 1, 0, l, bva);   // next tile's ks=0
        mfma_step(avv[3], bvb, acc);

        // hinge epilogue (covers next tile's in-flight loads)
        float ts = 0.f;
        #pragma unroll
        for (int m = 0; m < 4; ++m) {
            #pragma unroll
            for (int r4 = 0; r4 < 4; ++r4) {
                const int li = labi[m][r4];
                #pragma unroll
                for (int n = 0; n < 4; ++n) {
                    const float d = acc[m][n][r4];
                    const float v = (li == labj[n])
                        ? (d + (ALPHA_C - BETHE_C))
                        : ((ALPHA_C + BETHE_C) - d);
                    ts += fmaxf(v, 0.f);
                }
            }
        }
        lsum += (j == i) ? ts : 2.f * ts;
    }

    #pragma unroll
    for (int off = 32; off > 0; off >>= 1)
        lsum += __shfl_down(lsum, off, 64);
    if (l == 0) partials[blockIdx.x] = lsum;
}

// Final reduce: one block sums partials (fixed order -> deterministic).
__global__ __launch_bounds__(256) void reduce_kernel(
    const float* __restrict__ partials, float* __restrict__ out,
    int n, float inv_n)
{
    __shared__ float wsum[4];
    const int t    = threadIdx.x;
    const int lane = t & 63;
    const int wid  = t >> 6;
    float s = 0.f;
    for (int idx = t; idx < n; idx += 256) s += partials[idx];
    #pragma unroll
    for (int off = 32; off > 0; off >>= 1)
        s += __shfl_down(s, off, 64);
    if (lane == 0) wsum[wid] = s;
    __syncthreads();
    if (t == 0) out[0] = (wsum[0] + wsum[1] + wsum[2] + wsum[3]) * inv_n;
}

// ---------------- fallback (tiny ws / odd N): round-1 fused kernel ----------------
__global__ __launch_bounds__(256) void margin_tile_kernel(
    const float* __restrict__ X, const int* __restrict__ labels,
    float* __restrict__ out, int NT, float inv_n)
{
    __shared__ unsigned short ldsA[128 * 64];
    __shared__ unsigned short ldsB[128 * 64];
    __shared__ int labA[128];
    __shared__ int labB[128];
    __shared__ float wsum[4];

    int b = blockIdx.x;
    int ti = 0;
    while (b >= NT - ti) { b -= NT - ti; ++ti; }
    const int tj = ti + b;

    const int t    = threadIdx.x;
    const int lane = t & 63;
    const int wid  = t >> 6;
    const int wr   = wid >> 1;
    const int wc   = wid & 1;

    const int rowA = ti * 128;
    const int rowB = tj * 128;

    if (t < 128) labA[t] = labels[rowA + t];
    else         labB[t - 128] = labels[rowB + (t - 128)];

    frag_cd acc[4][4];
    #pragma unroll
    for (int m = 0; m < 4; ++m)
        #pragma unroll
        for (int n = 0; n < 4; ++n)
            acc[m][n] = (frag_cd){0.f, 0.f, 0.f, 0.f};

    const int g  = lane >> 4;
    const int rl = lane & 15;

    for (int kh = 0; kh < 2; ++kh) {
        __syncthreads();
        #pragma unroll
        for (int it = 0; it < 4; ++it) {
            const int c  = it * 256 + t;
            const int r  = c >> 3;
            const int c8 = c & 7;
            const float* srcA = X + (size_t)(rowA + r) * 128 + kh * 64 + c8 * 8;
            const float* srcB = X + (size_t)(rowB + r) * 128 + kh * 64 + c8 * 8;
            float4 a0 = *(const float4*)(srcA);
            float4 a1 = *(const float4*)(srcA + 4);
            float4 b0 = *(const float4*)(srcB);
            float4 b1 = *(const float4*)(srcB + 4);
            const int byte = r * 128 + (((c8 << 4)) ^ ((r & 7) << 4));
            frag_ab pa, pb;
            pa[0] = (short)f2bf(a0.x); pa[1] = (short)f2bf(a0.y);
            pa[2] = (short)f2bf(a0.z); pa[3] = (short)f2bf(a0.w);
            pa[4] = (short)f2bf(a1.x); pa[5] = (short)f2bf(a1.y);
            pa[6] = (short)f2bf(a1.z); pa[7] = (short)f2bf(a1.w);
            pb[0] = (short)f2bf(b0.x); pb[1] = (short)f2bf(b0.y);
            pb[2] = (short)f2bf(b0.z); pb[3] = (short)f2bf(b0.w);
            pb[4] = (short)f2bf(b1.x); pb[5] = (short)f2bf(b1.y);
            pb[6] = (short)f2bf(b1.z); pb[7] = (short)f2bf(b1.w);
            *(frag_ab*)((char*)ldsA + byte) = pa;
            *(frag_ab*)((char*)ldsB + byte) = pb;
        }
        __syncthreads();
        #pragma unroll
        for (int ks = 0; ks < 2; ++ks) {
            const int kbyte = ks * 64 + g * 16;
            frag_ab av[4], bv[4];
            #pragma unroll
            for (int m = 0; m < 4; ++m) {
                const int row = wr * 64 + m * 16 + rl;
                av[m] = *(const frag_ab*)((const char*)ldsA +
                            row * 128 + (kbyte ^ ((row & 7) << 4)));
            }
            #pragma unroll
            for (int n = 0; n < 4; ++n) {
                const int row = wc * 64 + n * 16 + rl;
                bv[n] = *(const frag_ab*)((const char*)ldsB +
                            row * 128 + (kbyte ^ ((row & 7) << 4)));
            }
            #pragma unroll
            for (int m = 0; m < 4; ++m)
                #pragma unroll
                for (int n = 0; n < 4; ++n)
                    acc[m][n] = __builtin_amdgcn_mfma_f32_16x16x32_bf16(
                        av[m], bv[n], acc[m][n], 0, 0, 0);
        }
    }

    float lsum = 0.f;
    const int oc  = lane & 15;
    const int orr = (lane >> 4) * 4;

    int lj[4];
    #pragma unroll
    for (int n = 0; n < 4; ++n) lj[n] = labB[wc * 64 + n * 16 + oc];

    #pragma unroll
    for (int m = 0; m < 4; ++m) {
        #pragma unroll
        for (int j = 0; j < 4; ++j) {
            const int li = labA[wr * 64 + m * 16 + orr + j];
            #pragma unroll
            for (int n = 0; n < 4; ++n) {
                const float d = acc[m][n][j];
                const float s = (li == lj[n]) ? 1.f : -1.f;
                lsum += fmaxf(fmaf(s, d - BETHE_C, ALPHA_C), 0.f);
            }
        }
    }

    const float w = (ti == tj) ? 1.f : 2.f;
    lsum *= w * inv_n;

    #pragma unroll
    for (int off = 32; off > 0; off >>= 1)
        lsum += __shfl_down(lsum, off, 64);

    if (lane == 0) wsum[wid] = lsum;
    __syncthreads();
    if (t == 0) atomicAdd(out, wsum[0] + wsum[1] + wsum[2] + wsum[3]);
}

extern "C" void kernel_launch(void* const* d_in, const int* in_sizes, int n_in,
                              void* d_out, int out_size, void* d_ws, size_t ws_size,
                              hipStream_t stream) {
    const float* X      = (const float*)d_in[0];
    const int*   labels = (const int*)d_in[1];
    float*       out    = (float*)d_out;

    const int N = in_sizes[1];               // 8192

    const size_t xb_bytes = (size_t)N * 128 * sizeof(unsigned short);  // 2 MB
    const int NP = N / 64;                   // 128 panels

    // exact triangular chunk count: sum over i of ceil((NP-i)/CH)
    int nblk = 0;
    for (int i = 0; i < NP; ++i) nblk += (NP - i + CH - 1) / CH;   // 2112 @ NP=128

    const size_t need = xb_bytes + (size_t)nblk * sizeof(float);

    if ((N % 64) == 0 && ws_size >= need) {
        unsigned short* Xb       = (unsigned short*)d_ws;
        float*          partials = (float*)((char*)d_ws + xb_bytes);
        const int cblocks = (N * 16 + 255) / 256;
        convert_kernel<<<cblocks, 256, 0, stream>>>(X, Xb, N);
        margin_reg<<<nblk, 64, 0, stream>>>(Xb, labels, partials, NP);
        reduce_kernel<<<1, 256, 0, stream>>>(partials, out, nblk, 1.0f / (float)N);
    } else {
        const int NT = N / 128;
        const int nblocks = NT * (NT + 1) / 2;
        zero_kernel<<<1, 1, 0, stream>>>(out);
        margin_tile_kernel<<<nblocks, 256, 0, stream>>>(X, labels, out, NT, 1.0f / (float)N);
    }
}